// Round 2
// baseline (307.513 us; speedup 1.0000x reference)
//
#include <hip/hip_runtime.h>
#include <hip/hip_bf16.h>

typedef __bf16 bf16x8 __attribute__((ext_vector_type(8)));
typedef float  f32x4  __attribute__((ext_vector_type(4)));
typedef unsigned u32x4v __attribute__((ext_vector_type(4)));

#define QSCALE 0.25f
#define LOG2E  1.4426950408889634f

// RNE f32 -> bf16 (plain C++, finite inputs)
static __device__ __forceinline__ unsigned short f2bf(float x) {
  unsigned u = __float_as_uint(x);
  return (unsigned short)((u + 0x7FFFu + ((u >> 16) & 1u)) >> 16);
}
static __device__ __forceinline__ unsigned pk2(float a, float b) {
  return (unsigned)f2bf(a) | ((unsigned)f2bf(b) << 16);
}
static __device__ __forceinline__ bf16x8 u2bf(u32x4v x) {
  union { u32x4v u; bf16x8 b; } c; c.u = x; return c.b;
}

// LDS tile rows of 128 B ([tok][ch] bf16); XOR-swizzle byte bits 4-6 by row&7.
// Preserves 16-B alignment for MFMA frag reads, breaks same-bank columns.
#define SWZ(tk, ch2b) ((unsigned)((tk) * 128 + ((ch2b) ^ (((tk) & 7) << 4))))

// ---------------------------------------------------------------------------
// Prologue: weights -> bf16 MFMA fragments in d_ws.
// u32 layout: [0,2048) WQ B-frags (8: f=nt*2+kt), [2048,6144) WKV B-frags (16),
// [6144,8192) WOUT^T A-frags (8), [8192,8448) f32 biases bq'|bkv|bout.
// Frag: lane l -> n/m = 16*tile + (l&15), k = kt*32 + (l>>4)*8 + elem.
// ---------------------------------------------------------------------------
__global__ void prep_weights(const float* __restrict__ wq, const float* __restrict__ wkv,
                             const float* __restrict__ wout, const float* __restrict__ bq,
                             const float* __restrict__ bkv, const float* __restrict__ bout,
                             unsigned* __restrict__ ws32) {
  const unsigned t = threadIdx.x;
  for (unsigned e = t; e < 2048; e += 256) {
    const unsigned fid = e >> 6, lane = e & 63;
    const unsigned l15 = lane & 15, g = lane >> 4;
    float v[8];
    if (fid < 8) {                     // WQ (scale*log2e folded)
      const unsigned nt = fid >> 1, kt = fid & 1, n = nt * 16 + l15;
#pragma unroll
      for (int i = 0; i < 8; ++i) v[i] = wq[(kt * 32 + g * 8 + i) * 64 + n] * (QSCALE * LOG2E);
    } else if (fid < 24) {             // WKV
      const unsigned f = fid - 8, nt = f >> 1, kt = f & 1, n = nt * 16 + l15;
#pragma unroll
      for (int i = 0; i < 8; ++i) v[i] = wkv[(kt * 32 + g * 8 + i) * 128 + n];
    } else {                           // WOUT^T: A[m=c_out][k=c_in] = wout[c_in][c_out]
      const unsigned f = fid - 24, mt = f >> 1, kt = f & 1, m = mt * 16 + l15;
#pragma unroll
      for (int i = 0; i < 8; ++i) v[i] = wout[(kt * 32 + g * 8 + i) * 64 + m];
    }
#pragma unroll
    for (int w = 0; w < 4; ++w) ws32[e * 4 + w] = pk2(v[2 * w], v[2 * w + 1]);
  }
  float* bws = (float*)(ws32 + 8192);
  if (t < 64)       bws[t] = bq[t] * (QSCALE * LOG2E);
  else if (t < 192) bws[t] = bkv[t - 64];
  else if (t < 256) bws[t] = bout[t - 192];
}

// ---------------------------------------------------------------------------
// Main: 1 block (4 waves) per 8x8 window; wave = head. Only 16x16x32 MFMA.
// LDS: buf0 [0,8K) q->q_proj->attn_out | buf1 [8K,16K) conv->K |
//      P [16K+wv*8K, 48K) probs per wave | VT [48K,56K) V^T rows=ch.
// ---------------------------------------------------------------------------
__launch_bounds__(256)
__global__ void fused_win_attn(const float* __restrict__ qf, const float* __restrict__ kvf,
                               const float* __restrict__ wdw, const unsigned* __restrict__ ws32,
                               float* __restrict__ out) {
  __shared__ __align__(16) char lds[57344];
  unsigned short* lds16 = (unsigned short*)lds;
  unsigned* lds32p = (unsigned*)lds;

  // XCD-chunked swizzle: consecutive launch-bids on one XCD sweep x-adjacent windows
  const unsigned bid = blockIdx.x;
  const unsigned wid = (bid & 7) * 1024 + (bid >> 3);
  const unsigned b = wid >> 10, rem = wid & 1023;
  const unsigned y0 = (rem >> 5) * 8, x0 = (rem & 31) * 8;

  const unsigned t = threadIdx.x;
  const unsigned lane = t & 63;
  const unsigned wv = t >> 6;           // wave id = head id
  const unsigned l15 = lane & 15, g = lane >> 4;
  const unsigned tok = lane;            // staging/conv: lane <-> token

  const unsigned PB = 16384u + wv * 8192u;   // this wave's P buffer
  const unsigned VT = 49152u;                // wait: see layout note below
  // NOTE: P spans [16384, 49152); VT at [49152, 57344)

  // ---- stage q window -> buf0 (all 256 threads) ----
  {
    const float* qb = qf + (size_t)b * 4194304 + (size_t)(y0 + (tok >> 3)) * 256 + x0 + (tok & 7);
#pragma unroll
    for (int p = 0; p < 8; ++p) {
      const unsigned ch = 2u * (wv + 4u * (unsigned)p);
      const float a0 = qb[(size_t)ch * 65536];
      const float a1 = qb[(size_t)(ch + 1) * 65536];
      lds32p[SWZ(tok, ch * 2) >> 2] = pk2(a0, a1);
    }
  }

  // ---- depthwise 3x3 conv (f32) -> buf1; wave wv does ch [wv*16, wv*16+16) ----
  {
    const int yy = (int)(y0 + (tok >> 3)), xx = (int)(x0 + (tok & 7));
    int off[9]; float msk[9];
#pragma unroll
    for (int dy = -1; dy <= 1; ++dy)
#pragma unroll
      for (int dx = -1; dx <= 1; ++dx) {
        const int k = (dy + 1) * 3 + (dx + 1);
        int yq = yy + dy, xq = xx + dx;
        const bool ok = (yq >= 0) && (yq < 256) && (xq >= 0) && (xq < 256);
        yq = yq < 0 ? 0 : (yq > 255 ? 255 : yq);
        xq = xq < 0 ? 0 : (xq > 255 ? 255 : xq);
        off[k] = yq * 256 + xq;
        msk[k] = ok ? 1.f : 0.f;
      }
    const bool interior = (y0 != 0) && (y0 != 248) && (x0 != 0) && (x0 != 248);
    const float* kb = kvf + (size_t)b * 4194304 + (size_t)(wv * 16) * 65536;
    const float* wp0 = wdw + wv * 16 * 9;
#pragma unroll
    for (int c2 = 0; c2 < 8; ++c2) {
      float acc[2];
#pragma unroll
      for (int hh = 0; hh < 2; ++hh) {
        const float* cb = kb + (size_t)(c2 * 2 + hh) * 65536;
        const float* wp = wp0 + (c2 * 2 + hh) * 9;
        float a = 0.f;
        if (interior) {
#pragma unroll
          for (int k = 0; k < 9; ++k) a = fmaf(cb[off[k]], wp[k], a);
        } else {
#pragma unroll
          for (int k = 0; k < 9; ++k) a = fmaf(cb[off[k]], wp[k] * msk[k], a);
        }
        acc[hh] = a;
      }
      lds32p[(8192u + SWZ(tok, (wv * 16 + c2 * 2) * 2)) >> 2] = pk2(acc[0], acc[1]);
    }
  }
  __syncthreads();  // barrier 1: staged q + conv visible

  // ---- read A-frags (q_win, kv_win over all 64 ch), weight B-frags, biases ----
  bf16x8 qA[4][2], kvA[4][2];
#pragma unroll
  for (int mt = 0; mt < 4; ++mt)
#pragma unroll
    for (int kt = 0; kt < 2; ++kt) {
      const unsigned byo = SWZ(mt * 16 + l15, (kt * 32 + g * 8) * 2);
      qA[mt][kt]  = *(const bf16x8*)(lds + byo);
      kvA[mt][kt] = *(const bf16x8*)(lds + 8192 + byo);
    }
  const bf16x8* wsf = (const bf16x8*)ws32;
  bf16x8 wqB[2], wkB[2], wvB[2];
#pragma unroll
  for (int kt = 0; kt < 2; ++kt) {
    wqB[kt] = wsf[(wv * 2 + kt) * 64 + lane];
    wkB[kt] = wsf[512 + (wv * 2 + kt) * 64 + lane];
    wvB[kt] = wsf[512 + ((4 + wv) * 2 + kt) * 64 + lane];
  }
  const float* bws = (const float*)(ws32 + 8192);
  const float bqv = bws[wv * 16 + l15];
  const float bkK = bws[64 + wv * 16 + l15];
  const float bkV = bws[128 + wv * 16 + l15];
  __syncthreads();  // barrier 2: frag reads done; buffers may be overwritten

  // ---- projections: q_proj / K / V for this head's 16 cols ----
  f32x4 qacc[4], kacc[4], vacc[4];
#pragma unroll
  for (int mt = 0; mt < 4; ++mt) {
    qacc[mt] = (f32x4){bqv, bqv, bqv, bqv};
    kacc[mt] = (f32x4){bkK, bkK, bkK, bkK};
    vacc[mt] = (f32x4){bkV, bkV, bkV, bkV};
  }
#pragma unroll
  for (int kt = 0; kt < 2; ++kt)
#pragma unroll
    for (int mt = 0; mt < 4; ++mt) {
      qacc[mt] = __builtin_amdgcn_mfma_f32_16x16x32_bf16(qA[mt][kt],  wqB[kt], qacc[mt], 0, 0, 0);
      kacc[mt] = __builtin_amdgcn_mfma_f32_16x16x32_bf16(kvA[mt][kt], wkB[kt], kacc[mt], 0, 0, 0);
      vacc[mt] = __builtin_amdgcn_mfma_f32_16x16x32_bf16(kvA[mt][kt], wvB[kt], vacc[mt], 0, 0, 0);
    }
  // C-map (verified): col = l&15, row = (l>>4)*4 + r
  // q_proj -> buf0 own cols, K -> buf1 own cols, V^T -> VT own rows (all wave-local)
#pragma unroll
  for (int mt = 0; mt < 4; ++mt)
#pragma unroll
    for (int r = 0; r < 4; ++r) {
      const unsigned tk = mt * 16 + g * 4 + r;
      const unsigned byo = SWZ(tk, (wv * 16 + l15) * 2);
      lds16[byo >> 1] = f2bf(qacc[mt][r]);
      lds16[(8192u + byo) >> 1] = f2bf(kacc[mt][r]);
      lds16[(49152u + SWZ(wv * 16 + l15, tk * 2)) >> 1] = f2bf(vacc[mt][r]);
    }

  // ---- QK^T: x32 MFMA with zero-padded K (16 real ch + 16 zeros) ----
  // Mask is per-(g,elem) slot => correct under any frag k-map (A,B consistent).
  const unsigned padmask = (g < 2) ? 0xFFFFFFFFu : 0u;
  bf16x8 kA32[4], qB32[4];
#pragma unroll
  for (int mt = 0; mt < 4; ++mt) {
    const unsigned byo = SWZ(mt * 16 + l15, (wv * 16 + (g & 1) * 8) * 2);
    u32x4v ka = *(const u32x4v*)(lds + 8192 + byo);
    u32x4v qa = *(const u32x4v*)(lds + byo);
    ka &= padmask; qa &= padmask;
    kA32[mt] = u2bf(ka);
    qB32[mt] = u2bf(qa);
  }
  const f32x4 zero4 = (f32x4){0.f, 0.f, 0.f, 0.f};
  f32x4 sc[4][4];   // scores^T: col = tok1 = l&15, row = tok2 = (l>>4)*4 + r
#pragma unroll
  for (int mt = 0; mt < 4; ++mt)
#pragma unroll
    for (int nt = 0; nt < 4; ++nt)
      sc[mt][nt] = __builtin_amdgcn_mfma_f32_16x16x32_bf16(kA32[mt], qB32[nt], zero4, 0, 0, 0);

  // ---- softmax over tok2 per column tok1 (exp2 domain; scale folded in wq) ----
  float sinv[4];
#pragma unroll
  for (int nt = 0; nt < 4; ++nt) {
    float m = sc[0][nt][0];
#pragma unroll
    for (int mt = 0; mt < 4; ++mt)
#pragma unroll
      for (int r = 0; r < 4; ++r) m = fmaxf(m, sc[mt][nt][r]);
    m = fmaxf(m, __shfl_xor(m, 16));
    m = fmaxf(m, __shfl_xor(m, 32));
    float sum = 0.f;
#pragma unroll
    for (int mt = 0; mt < 4; ++mt)
#pragma unroll
      for (int r = 0; r < 4; ++r) {
        const float e = exp2f(sc[mt][nt][r] - m);
        sc[mt][nt][r] = e;
        sum += e;
      }
    sum += __shfl_xor(sum, 16);
    sum += __shfl_xor(sum, 32);
    sinv[nt] = 1.0f / sum;
  }

  // ---- P (normalized probs) -> P_lds[tok1][tok2], wave-private ----
#pragma unroll
  for (int nt = 0; nt < 4; ++nt)
#pragma unroll
    for (int mt = 0; mt < 4; ++mt)
#pragma unroll
      for (int r = 0; r < 4; ++r)
        lds16[(PB + SWZ(nt * 16 + l15, (mt * 16 + g * 4 + r) * 2)) >> 1] =
            f2bf(sc[mt][nt][r] * sinv[nt]);

  // ---- PV: out^T[ch][tok1] = V^T · P^T, K = tok2 = 64 (2 x32 steps) ----
  f32x4 oacc[4];
#pragma unroll
  for (int nt = 0; nt < 4; ++nt) oacc[nt] = zero4;
#pragma unroll
  for (int kt = 0; kt < 2; ++kt) {
    const bf16x8 vA = *(const bf16x8*)(lds + 49152 + SWZ(wv * 16 + l15, (kt * 32 + g * 8) * 2));
#pragma unroll
    for (int nt = 0; nt < 4; ++nt) {
      const bf16x8 pB = *(const bf16x8*)(lds + PB + SWZ(nt * 16 + l15, (kt * 32 + g * 8) * 2));
      oacc[nt] = __builtin_amdgcn_mfma_f32_16x16x32_bf16(vA, pB, oacc[nt], 0, 0, 0);
    }
  }
  // attn_out[tok][wv*16 + g*4 + r] -> buf0 own cols (D: col=tok1=l&15, row=ch_loc=g*4+r)
#pragma unroll
  for (int nt = 0; nt < 4; ++nt)
#pragma unroll
    for (int r = 0; r < 4; ++r)
      lds16[SWZ(nt * 16 + l15, (wv * 16 + g * 4 + r) * 2) >> 1] = f2bf(oacc[nt][r]);
  __syncthreads();  // barrier 3: attn_out exchange

  // ---- output projection: final^T[c_out][tok], wave owns c_out tile wv ----
  bf16x8 woA[2];
#pragma unroll
  for (int kt = 0; kt < 2; ++kt) woA[kt] = wsf[1536 + (wv * 2 + kt) * 64 + lane];
  float bo[4];
#pragma unroll
  for (int r = 0; r < 4; ++r) bo[r] = bws[192 + wv * 16 + g * 4 + r];
  f32x4 facc[4];
#pragma unroll
  for (int nt = 0; nt < 4; ++nt) facc[nt] = (f32x4){bo[0], bo[1], bo[2], bo[3]};
#pragma unroll
  for (int nt = 0; nt < 4; ++nt)
#pragma unroll
    for (int kt = 0; kt < 2; ++kt) {
      const unsigned byo = SWZ(nt * 16 + l15, (kt * 32 + g * 8) * 2);
      const bf16x8 aB = *(const bf16x8*)(lds + byo);
      facc[nt] = __builtin_amdgcn_mfma_f32_16x16x32_bf16(woA[kt], aB, facc[nt], 0, 0, 0);
    }
  float* ob = out + (size_t)b * 4194304 + (size_t)(wv * 16) * 65536 + (size_t)y0 * 256 + x0;
#pragma unroll
  for (int nt = 0; nt < 4; ++nt)
#pragma unroll
    for (int r = 0; r < 4; ++r) {
      const unsigned tk = nt * 16 + l15;
      ob[(size_t)(g * 4 + r) * 65536 + (tk >> 3) * 256 + (tk & 7)] = facc[nt][r];
    }
  (void)VT;
}

extern "C" void kernel_launch(void* const* d_in, const int* in_sizes, int n_in,
                              void* d_out, int out_size, void* d_ws, size_t ws_size,
                              hipStream_t stream) {
  const float* qf   = (const float*)d_in[0];
  const float* kvf  = (const float*)d_in[1];
  const float* wq   = (const float*)d_in[2];
  const float* bq   = (const float*)d_in[3];
  const float* wkv  = (const float*)d_in[4];
  const float* bkv  = (const float*)d_in[5];
  const float* wdw  = (const float*)d_in[6];
  const float* wout = (const float*)d_in[7];
  const float* bout = (const float*)d_in[8];
  (void)in_sizes; (void)n_in; (void)out_size; (void)ws_size;

  prep_weights<<<1, 256, 0, stream>>>(wq, wkv, wout, bq, bkv, bout, (unsigned*)d_ws);
  fused_win_attn<<<8192, 256, 0, stream>>>(qf, kvf, wdw, (const unsigned*)d_ws, (float*)d_out);
}

// Round 3
// 297.653 us; speedup vs baseline: 1.0331x; 1.0331x over previous
//
#include <hip/hip_runtime.h>
#include <hip/hip_bf16.h>

typedef __bf16 bf16x8 __attribute__((ext_vector_type(8)));
typedef float  f32x4  __attribute__((ext_vector_type(4)));
typedef unsigned u32x4v __attribute__((ext_vector_type(4)));

#define QSCALE 0.25f
#define LOG2E  1.4426950408889634f

// RNE f32 -> bf16 (plain C++, finite inputs)
static __device__ __forceinline__ unsigned short f2bf(float x) {
  unsigned u = __float_as_uint(x);
  return (unsigned short)((u + 0x7FFFu + ((u >> 16) & 1u)) >> 16);
}
static __device__ __forceinline__ unsigned pk2(float a, float b) {
  return (unsigned)f2bf(a) | ((unsigned)f2bf(b) << 16);
}
static __device__ __forceinline__ bf16x8 u2bf(u32x4v x) {
  union { u32x4v u; bf16x8 b; } c; c.u = x; return c.b;
}

// LDS tile rows of 128 B ([tok][ch] bf16); XOR-swizzle byte bits 4-6 by row&7.
#define SWZ(tk, ch2b) ((unsigned)((tk) * 128 + ((ch2b) ^ (((tk) & 7) << 4))))

// ---------------------------------------------------------------------------
// Prologue: weights -> bf16 MFMA fragments in d_ws.
// u32 layout: [0,2048) WQ B-frags (8: f=nt*2+kt), [2048,6144) WKV B-frags (16),
// [6144,8192) WOUT^T A-frags (8), [8192,8448) f32 biases bq'|bkv|bout.
// Frag: lane l -> n/m = 16*tile + (l&15), k = kt*32 + (l>>4)*8 + elem.
// ---------------------------------------------------------------------------
__global__ void prep_weights(const float* __restrict__ wq, const float* __restrict__ wkv,
                             const float* __restrict__ wout, const float* __restrict__ bq,
                             const float* __restrict__ bkv, const float* __restrict__ bout,
                             unsigned* __restrict__ ws32) {
  const unsigned t = threadIdx.x;
  for (unsigned e = t; e < 2048; e += 256) {
    const unsigned fid = e >> 6, lane = e & 63;
    const unsigned l15 = lane & 15, g = lane >> 4;
    float v[8];
    if (fid < 8) {                     // WQ (scale*log2e folded)
      const unsigned nt = fid >> 1, kt = fid & 1, n = nt * 16 + l15;
#pragma unroll
      for (int i = 0; i < 8; ++i) v[i] = wq[(kt * 32 + g * 8 + i) * 64 + n] * (QSCALE * LOG2E);
    } else if (fid < 24) {             // WKV
      const unsigned f = fid - 8, nt = f >> 1, kt = f & 1, n = nt * 16 + l15;
#pragma unroll
      for (int i = 0; i < 8; ++i) v[i] = wkv[(kt * 32 + g * 8 + i) * 128 + n];
    } else {                           // WOUT^T: A[m=c_out][k=c_in] = wout[c_in][c_out]
      const unsigned f = fid - 24, mt = f >> 1, kt = f & 1, m = mt * 16 + l15;
#pragma unroll
      for (int i = 0; i < 8; ++i) v[i] = wout[(kt * 32 + g * 8 + i) * 64 + m];
    }
#pragma unroll
    for (int w = 0; w < 4; ++w) ws32[e * 4 + w] = pk2(v[2 * w], v[2 * w + 1]);
  }
  float* bws = (float*)(ws32 + 8192);
  if (t < 64)       bws[t] = bq[t] * (QSCALE * LOG2E);
  else if (t < 192) bws[t] = bkv[t - 64];
  else if (t < 256) bws[t] = bout[t - 192];
}

// ---------------------------------------------------------------------------
// Main: 1 block (4 waves) per 8x8 window; wave = head. Only 16x16x32 MFMA.
// LDS: buf0 [0,8K) q->q_proj->attn_out | buf1 [8K,16K) conv->K.
// P and V^T never touch LDS: their projection/QK^T C-fragments are consumed
// directly as PV A/B-fragments under a consistent bijective slot->tok2 map.
// ---------------------------------------------------------------------------
__launch_bounds__(256)
__global__ void fused_win_attn(const float* __restrict__ qf, const float* __restrict__ kvf,
                               const float* __restrict__ wdw, const unsigned* __restrict__ ws32,
                               float* __restrict__ out) {
  __shared__ __align__(16) char lds[16384];
  unsigned short* lds16 = (unsigned short*)lds;
  unsigned* lds32p = (unsigned*)lds;

  // XCD-chunked swizzle: consecutive launch-bids on one XCD sweep x-adjacent windows
  const unsigned bid = blockIdx.x;
  const unsigned wid = (bid & 7) * 1024 + (bid >> 3);
  const unsigned b = wid >> 10, rem = wid & 1023;
  const unsigned y0 = (rem >> 5) * 8, x0 = (rem & 31) * 8;

  const unsigned t = threadIdx.x;
  const unsigned lane = t & 63;
  const unsigned wv = t >> 6;           // wave id = head id
  const unsigned l15 = lane & 15, g = lane >> 4;
  const unsigned tok = lane;            // staging/conv: lane <-> token

  // ---- stage q window -> buf0 (all 256 threads) ----
  {
    const float* qb = qf + (size_t)b * 4194304 + (size_t)(y0 + (tok >> 3)) * 256 + x0 + (tok & 7);
#pragma unroll
    for (int p = 0; p < 8; ++p) {
      const unsigned ch = 2u * (wv + 4u * (unsigned)p);
      const float a0 = qb[(size_t)ch * 65536];
      const float a1 = qb[(size_t)(ch + 1) * 65536];
      lds32p[SWZ(tok, ch * 2) >> 2] = pk2(a0, a1);
    }
  }

  // ---- depthwise 3x3 conv (f32) -> buf1; wave wv does ch [wv*16, wv*16+16) ----
  {
    const int yy = (int)(y0 + (tok >> 3)), xx = (int)(x0 + (tok & 7));
    int off[9]; float msk[9];
#pragma unroll
    for (int dy = -1; dy <= 1; ++dy)
#pragma unroll
      for (int dx = -1; dx <= 1; ++dx) {
        const int k = (dy + 1) * 3 + (dx + 1);
        int yq = yy + dy, xq = xx + dx;
        const bool ok = (yq >= 0) && (yq < 256) && (xq >= 0) && (xq < 256);
        yq = yq < 0 ? 0 : (yq > 255 ? 255 : yq);
        xq = xq < 0 ? 0 : (xq > 255 ? 255 : xq);
        off[k] = yq * 256 + xq;
        msk[k] = ok ? 1.f : 0.f;
      }
    const bool interior = (y0 != 0) && (y0 != 248) && (x0 != 0) && (x0 != 248);
    const float* kb = kvf + (size_t)b * 4194304 + (size_t)(wv * 16) * 65536;
    const float* wp0 = wdw + wv * 16 * 9;
#pragma unroll
    for (int c2 = 0; c2 < 8; ++c2) {
      float acc[2];
#pragma unroll
      for (int hh = 0; hh < 2; ++hh) {
        const float* cb = kb + (size_t)(c2 * 2 + hh) * 65536;
        const float* wp = wp0 + (c2 * 2 + hh) * 9;
        float a = 0.f;
        if (interior) {
#pragma unroll
          for (int k = 0; k < 9; ++k) a = fmaf(cb[off[k]], wp[k], a);
        } else {
#pragma unroll
          for (int k = 0; k < 9; ++k) a = fmaf(cb[off[k]], wp[k] * msk[k], a);
        }
        acc[hh] = a;
      }
      lds32p[(8192u + SWZ(tok, (wv * 16 + c2 * 2) * 2)) >> 2] = pk2(acc[0], acc[1]);
    }
  }
  __syncthreads();  // barrier 1: staged q + conv visible

  // ---- read A-frags (q_win, kv_win over all 64 ch), weight B-frags, biases ----
  bf16x8 qA[4][2], kvA[4][2];
#pragma unroll
  for (int mt = 0; mt < 4; ++mt)
#pragma unroll
    for (int kt = 0; kt < 2; ++kt) {
      const unsigned byo = SWZ(mt * 16 + l15, (kt * 32 + g * 8) * 2);
      qA[mt][kt]  = *(const bf16x8*)(lds + byo);
      kvA[mt][kt] = *(const bf16x8*)(lds + 8192 + byo);
    }
  const bf16x8* wsf = (const bf16x8*)ws32;
  bf16x8 wqB[2], wkB[2], wvB[2];
#pragma unroll
  for (int kt = 0; kt < 2; ++kt) {
    wqB[kt] = wsf[(wv * 2 + kt) * 64 + lane];
    wkB[kt] = wsf[512 + (wv * 2 + kt) * 64 + lane];
    wvB[kt] = wsf[512 + ((4 + wv) * 2 + kt) * 64 + lane];
  }
  const float* bws = (const float*)(ws32 + 8192);
  const float bqv = bws[wv * 16 + l15];
  const float bkK = bws[64 + wv * 16 + l15];
  const float bkV = bws[128 + wv * 16 + l15];
  __syncthreads();  // barrier 2: frag reads done; buffers may be overwritten

  // ---- projections: q_proj / K / V for this head's 16 cols ----
  f32x4 qacc[4], kacc[4], vacc[4];
#pragma unroll
  for (int mt = 0; mt < 4; ++mt) {
    qacc[mt] = (f32x4){bqv, bqv, bqv, bqv};
    kacc[mt] = (f32x4){bkK, bkK, bkK, bkK};
    vacc[mt] = (f32x4){bkV, bkV, bkV, bkV};
  }
#pragma unroll
  for (int kt = 0; kt < 2; ++kt)
#pragma unroll
    for (int mt = 0; mt < 4; ++mt) {
      qacc[mt] = __builtin_amdgcn_mfma_f32_16x16x32_bf16(qA[mt][kt],  wqB[kt], qacc[mt], 0, 0, 0);
      kacc[mt] = __builtin_amdgcn_mfma_f32_16x16x32_bf16(kvA[mt][kt], wkB[kt], kacc[mt], 0, 0, 0);
      vacc[mt] = __builtin_amdgcn_mfma_f32_16x16x32_bf16(kvA[mt][kt], wvB[kt], vacc[mt], 0, 0, 0);
    }
  // C-map (verified): col = l&15, row = (l>>4)*4 + r
  // q_proj -> buf0 own cols, K -> buf1 own cols (wave-local; V stays in regs)
#pragma unroll
  for (int mt = 0; mt < 4; ++mt)
#pragma unroll
    for (int r = 0; r < 4; ++r) {
      const unsigned tk = mt * 16 + g * 4 + r;
      const unsigned byo = SWZ(tk, (wv * 16 + l15) * 2);
      lds16[byo >> 1] = f2bf(qacc[mt][r]);
      lds16[(8192u + byo) >> 1] = f2bf(kacc[mt][r]);
    }

  // ---- QK^T: x32 MFMA with zero-padded K (16 real ch + 16 zeros) ----
  const unsigned padmask = (g < 2) ? 0xFFFFFFFFu : 0u;
  bf16x8 kA32[4], qB32[4];
#pragma unroll
  for (int mt = 0; mt < 4; ++mt) {
    const unsigned byo = SWZ(mt * 16 + l15, (wv * 16 + (g & 1) * 8) * 2);
    u32x4v ka = *(const u32x4v*)(lds + 8192 + byo);
    u32x4v qa = *(const u32x4v*)(lds + byo);
    ka &= padmask; qa &= padmask;
    kA32[mt] = u2bf(ka);
    qB32[mt] = u2bf(qa);
  }
  const f32x4 zero4 = (f32x4){0.f, 0.f, 0.f, 0.f};
  f32x4 sc[4][4];   // scores^T: col = tok1 = l&15, row = tok2 = (l>>4)*4 + r
#pragma unroll
  for (int mt = 0; mt < 4; ++mt)
#pragma unroll
    for (int nt = 0; nt < 4; ++nt)
      sc[mt][nt] = __builtin_amdgcn_mfma_f32_16x16x32_bf16(kA32[mt], qB32[nt], zero4, 0, 0, 0);

  // ---- softmax over tok2 per column tok1 (exp2 domain; scale folded in wq) ----
  // P left unnormalized; 1/sum folded into PV output (per-lane: tok1 = l15).
  float sinv[4];
#pragma unroll
  for (int nt = 0; nt < 4; ++nt) {
    float m = sc[0][nt][0];
#pragma unroll
    for (int mt = 0; mt < 4; ++mt)
#pragma unroll
      for (int r = 0; r < 4; ++r) m = fmaxf(m, sc[mt][nt][r]);
    m = fmaxf(m, __shfl_xor(m, 16));
    m = fmaxf(m, __shfl_xor(m, 32));
    float sum = 0.f;
#pragma unroll
    for (int mt = 0; mt < 4; ++mt)
#pragma unroll
      for (int r = 0; r < 4; ++r) {
        const float e = exp2f(sc[mt][nt][r] - m);
        sc[mt][nt][r] = e;
        sum += e;
      }
    sum += __shfl_xor(sum, 16);
    sum += __shfl_xor(sum, 32);
    sinv[nt] = 1.0f / sum;
  }

  // ---- repack P and V C-frags as PV B/A-frags in-lane (no LDS, no shuffles).
  // Consistent bijection: slot (kt, g, e=2j+eb) -> tok2 = (2kt+(j>>1))*16 + g*4 + 2*(j&1) + eb
  unsigned pw[4][4][2];  // [mt][nt][h] = pk2(P~[tok2=mt*16+g*4+2h(+1)][tok1 nt,l15])
  unsigned vw[4][2];     // [mt][h]     = pk2(V[tok2=mt*16+g*4+2h(+1)][ch=wv*16+l15])
#pragma unroll
  for (int mt = 0; mt < 4; ++mt) {
#pragma unroll
    for (int nt = 0; nt < 4; ++nt)
#pragma unroll
      for (int h = 0; h < 2; ++h)
        pw[mt][nt][h] = pk2(sc[mt][nt][2 * h], sc[mt][nt][2 * h + 1]);
#pragma unroll
    for (int h = 0; h < 2; ++h)
      vw[mt][h] = pk2(vacc[mt][2 * h], vacc[mt][2 * h + 1]);
  }

  // ---- PV: out^T[ch_loc][tok1] = V^T · P~^T over tok2 (2 x32 steps) ----
  f32x4 oacc[4];
#pragma unroll
  for (int nt = 0; nt < 4; ++nt) oacc[nt] = zero4;
#pragma unroll
  for (int kt = 0; kt < 2; ++kt) {
    const bf16x8 vA = u2bf((u32x4v){vw[2 * kt][0], vw[2 * kt][1],
                                    vw[2 * kt + 1][0], vw[2 * kt + 1][1]});
#pragma unroll
    for (int nt = 0; nt < 4; ++nt) {
      const bf16x8 pB = u2bf((u32x4v){pw[2 * kt][nt][0], pw[2 * kt][nt][1],
                                      pw[2 * kt + 1][nt][0], pw[2 * kt + 1][nt][1]});
      oacc[nt] = __builtin_amdgcn_mfma_f32_16x16x32_bf16(vA, pB, oacc[nt], 0, 0, 0);
    }
  }
  // attn_out[tok][wv*16 + g*4 + r] -> buf0 own cols (D: col=tok1=l&15, row=ch_loc=g*4+r)
#pragma unroll
  for (int nt = 0; nt < 4; ++nt)
#pragma unroll
    for (int r = 0; r < 4; ++r)
      lds16[SWZ(nt * 16 + l15, (wv * 16 + g * 4 + r) * 2) >> 1] = f2bf(oacc[nt][r] * sinv[nt]);
  __syncthreads();  // barrier 3: attn_out exchange

  // ---- output projection: final^T[c_out][tok], wave owns c_out tile wv ----
  bf16x8 woA[2];
#pragma unroll
  for (int kt = 0; kt < 2; ++kt) woA[kt] = wsf[1536 + (wv * 2 + kt) * 64 + lane];
  float bo[4];
#pragma unroll
  for (int r = 0; r < 4; ++r) bo[r] = bws[192 + wv * 16 + g * 4 + r];
  f32x4 facc[4];
#pragma unroll
  for (int nt = 0; nt < 4; ++nt) facc[nt] = (f32x4){bo[0], bo[1], bo[2], bo[3]};
#pragma unroll
  for (int nt = 0; nt < 4; ++nt)
#pragma unroll
    for (int kt = 0; kt < 2; ++kt) {
      const unsigned byo = SWZ(nt * 16 + l15, (kt * 32 + g * 8) * 2);
      const bf16x8 aB = *(const bf16x8*)(lds + byo);
      facc[nt] = __builtin_amdgcn_mfma_f32_16x16x32_bf16(woA[kt], aB, facc[nt], 0, 0, 0);
    }
  float* ob = out + (size_t)b * 4194304 + (size_t)(wv * 16) * 65536 + (size_t)y0 * 256 + x0;
#pragma unroll
  for (int nt = 0; nt < 4; ++nt)
#pragma unroll
    for (int r = 0; r < 4; ++r) {
      const unsigned tk = nt * 16 + l15;
      ob[(size_t)(g * 4 + r) * 65536 + (tk >> 3) * 256 + (tk & 7)] = facc[nt][r];
    }
}

extern "C" void kernel_launch(void* const* d_in, const int* in_sizes, int n_in,
                              void* d_out, int out_size, void* d_ws, size_t ws_size,
                              hipStream_t stream) {
  const float* qf   = (const float*)d_in[0];
  const float* kvf  = (const float*)d_in[1];
  const float* wq   = (const float*)d_in[2];
  const float* bq   = (const float*)d_in[3];
  const float* wkv  = (const float*)d_in[4];
  const float* bkv  = (const float*)d_in[5];
  const float* wdw  = (const float*)d_in[6];
  const float* wout = (const float*)d_in[7];
  const float* bout = (const float*)d_in[8];
  (void)in_sizes; (void)n_in; (void)out_size; (void)ws_size;

  prep_weights<<<1, 256, 0, stream>>>(wq, wkv, wout, bq, bkv, bout, (unsigned*)d_ws);
  fused_win_attn<<<8192, 256, 0, stream>>>(qf, kvf, wdw, (const unsigned*)d_ws, (float*)d_out);
}

// Round 4
// 218.994 us; speedup vs baseline: 1.4042x; 1.3592x over previous
//
#include <hip/hip_runtime.h>
#include <hip/hip_bf16.h>

typedef __bf16 bf16x8 __attribute__((ext_vector_type(8)));
typedef float  f32x4  __attribute__((ext_vector_type(4)));
typedef unsigned u32x4v __attribute__((ext_vector_type(4)));

#define QSCALE 0.25f
#define LOG2E  1.4426950408889634f

// RNE f32 -> bf16 (plain C++, finite inputs)
static __device__ __forceinline__ unsigned short f2bf(float x) {
  unsigned u = __float_as_uint(x);
  return (unsigned short)((u + 0x7FFFu + ((u >> 16) & 1u)) >> 16);
}
static __device__ __forceinline__ unsigned pk2(float a, float b) {
  return (unsigned)f2bf(a) | ((unsigned)f2bf(b) << 16);
}
static __device__ __forceinline__ bf16x8 u2bf(u32x4v x) {
  union { u32x4v u; bf16x8 b; } c; c.u = x; return c.b;
}

// LDS tile rows of 128 B ([tok][ch] bf16); XOR-swizzle byte bits 4-6 by row&7.
#define SWZ(tk, ch2b) ((unsigned)((tk) * 128 + ((ch2b) ^ (((tk) & 7) << 4))))

// ---------------------------------------------------------------------------
// Prologue: weights -> bf16 MFMA fragments in d_ws.
// u32 layout: [0,2048) WQ B-frags (8: f=nt*2+kt), [2048,6144) WKV B-frags (16),
// [6144,8192) WOUT^T A-frags (8), [8192,8448) f32 biases bq'|bkv|bout.
// Frag: lane l -> n/m = 16*tile + (l&15), k = kt*32 + (l>>4)*8 + elem.
// ---------------------------------------------------------------------------
__global__ void prep_weights(const float* __restrict__ wq, const float* __restrict__ wkv,
                             const float* __restrict__ wout, const float* __restrict__ bq,
                             const float* __restrict__ bkv, const float* __restrict__ bout,
                             unsigned* __restrict__ ws32) {
  const unsigned t = threadIdx.x;
  for (unsigned e = t; e < 2048; e += 256) {
    const unsigned fid = e >> 6, lane = e & 63;
    const unsigned l15 = lane & 15, g = lane >> 4;
    float v[8];
    if (fid < 8) {                     // WQ (scale*log2e folded)
      const unsigned nt = fid >> 1, kt = fid & 1, n = nt * 16 + l15;
#pragma unroll
      for (int i = 0; i < 8; ++i) v[i] = wq[(kt * 32 + g * 8 + i) * 64 + n] * (QSCALE * LOG2E);
    } else if (fid < 24) {             // WKV
      const unsigned f = fid - 8, nt = f >> 1, kt = f & 1, n = nt * 16 + l15;
#pragma unroll
      for (int i = 0; i < 8; ++i) v[i] = wkv[(kt * 32 + g * 8 + i) * 128 + n];
    } else {                           // WOUT^T: A[m=c_out][k=c_in] = wout[c_in][c_out]
      const unsigned f = fid - 24, mt = f >> 1, kt = f & 1, m = mt * 16 + l15;
#pragma unroll
      for (int i = 0; i < 8; ++i) v[i] = wout[(kt * 32 + g * 8 + i) * 64 + m];
    }
#pragma unroll
    for (int w = 0; w < 4; ++w) ws32[e * 4 + w] = pk2(v[2 * w], v[2 * w + 1]);
  }
  float* bws = (float*)(ws32 + 8192);
  if (t < 64)       bws[t] = bq[t] * (QSCALE * LOG2E);
  else if (t < 192) bws[t] = bkv[t - 64];
  else if (t < 256) bws[t] = bout[t - 192];
}

// ---------------------------------------------------------------------------
// Main: 1 block (4 waves) per 8x8 window; wave = head. Only 16x16x32 MFMA.
// LDS: buf0 [0,8K) q-window -> (after bar2) attn_out
//      buf1 [8K,16K) conv kv
//      buf2 [16K,24K) q_proj   buf3 [24K,32K) K
// P and V^T never touch LDS (C-frag -> A/B-frag bijection, in-lane repack).
// __launch_bounds__(256,4): cap unified VGPR+AGPR at 128 -> 4 blocks/CU.
// ---------------------------------------------------------------------------
__launch_bounds__(256, 4)
__global__ void fused_win_attn(const float* __restrict__ qf, const float* __restrict__ kvf,
                               const float* __restrict__ wdw, const unsigned* __restrict__ ws32,
                               float* __restrict__ out) {
  __shared__ __align__(16) char lds[32768];
  unsigned short* lds16 = (unsigned short*)lds;
  unsigned* lds32p = (unsigned*)lds;

  // XCD-chunked swizzle: consecutive launch-bids on one XCD sweep x-adjacent windows
  const unsigned bid = blockIdx.x;
  const unsigned wid = (bid & 7) * 1024 + (bid >> 3);
  const unsigned b = wid >> 10, rem = wid & 1023;
  const unsigned y0 = (rem >> 5) * 8, x0 = (rem & 31) * 8;

  const unsigned t = threadIdx.x;
  const unsigned lane = t & 63;
  const unsigned wv = t >> 6;           // wave id = head id
  const unsigned l15 = lane & 15, g = lane >> 4;
  const unsigned tok = lane;            // staging/conv: lane <-> token

  // ---- stage q window -> buf0 (all 256 threads) ----
  {
    const float* qb = qf + (size_t)b * 4194304 + (size_t)(y0 + (tok >> 3)) * 256 + x0 + (tok & 7);
#pragma unroll
    for (int p = 0; p < 8; ++p) {
      const unsigned ch = 2u * (wv + 4u * (unsigned)p);
      const float a0 = qb[(size_t)ch * 65536];
      const float a1 = qb[(size_t)(ch + 1) * 65536];
      lds32p[SWZ(tok, ch * 2) >> 2] = pk2(a0, a1);
    }
  }

  // ---- depthwise 3x3 conv (f32) -> buf1; wave wv does ch [wv*16, wv*16+16) ----
  {
    const int yy = (int)(y0 + (tok >> 3)), xx = (int)(x0 + (tok & 7));
    int off[9]; float msk[9];
#pragma unroll
    for (int dy = -1; dy <= 1; ++dy)
#pragma unroll
      for (int dx = -1; dx <= 1; ++dx) {
        const int k = (dy + 1) * 3 + (dx + 1);
        int yq = yy + dy, xq = xx + dx;
        const bool ok = (yq >= 0) && (yq < 256) && (xq >= 0) && (xq < 256);
        yq = yq < 0 ? 0 : (yq > 255 ? 255 : yq);
        xq = xq < 0 ? 0 : (xq > 255 ? 255 : xq);
        off[k] = yq * 256 + xq;
        msk[k] = ok ? 1.f : 0.f;
      }
    const bool interior = (y0 != 0) && (y0 != 248) && (x0 != 0) && (x0 != 248);
    const float* kb = kvf + (size_t)b * 4194304 + (size_t)(wv * 16) * 65536;
    const float* wp0 = wdw + wv * 16 * 9;
#pragma unroll
    for (int c2 = 0; c2 < 8; ++c2) {
      float acc[2];
#pragma unroll
      for (int hh = 0; hh < 2; ++hh) {
        const float* cb = kb + (size_t)(c2 * 2 + hh) * 65536;
        const float* wp = wp0 + (c2 * 2 + hh) * 9;
        float a = 0.f;
        if (interior) {
#pragma unroll
          for (int k = 0; k < 9; ++k) a = fmaf(cb[off[k]], wp[k], a);
        } else {
#pragma unroll
          for (int k = 0; k < 9; ++k) a = fmaf(cb[off[k]], wp[k] * msk[k], a);
        }
        acc[hh] = a;
      }
      lds32p[(8192u + SWZ(tok, (wv * 16 + c2 * 2) * 2)) >> 2] = pk2(acc[0], acc[1]);
    }
  }
  __syncthreads();  // barrier 1: staged q + conv visible

  const bf16x8* wsf = (const bf16x8*)ws32;
  const float* bws = (const float*)(ws32 + 8192);
  const f32x4 zero4 = (f32x4){0.f, 0.f, 0.f, 0.f};

  // ---- phase Q: q_proj for this head's 16 cols -> buf2 (qA dies before KV phase) ----
  {
    const float bqv = bws[wv * 16 + l15];
    f32x4 qacc[4];
#pragma unroll
    for (int mt = 0; mt < 4; ++mt) qacc[mt] = (f32x4){bqv, bqv, bqv, bqv};
#pragma unroll
    for (int kt = 0; kt < 2; ++kt) {
      const bf16x8 wqB = wsf[(wv * 2 + kt) * 64 + lane];
#pragma unroll
      for (int mt = 0; mt < 4; ++mt) {
        const bf16x8 qA = *(const bf16x8*)(lds + SWZ(mt * 16 + l15, (kt * 32 + g * 8) * 2));
        qacc[mt] = __builtin_amdgcn_mfma_f32_16x16x32_bf16(qA, wqB, qacc[mt], 0, 0, 0);
      }
    }
    // C-map (verified): col = l&15, row = (l>>4)*4 + r
#pragma unroll
    for (int mt = 0; mt < 4; ++mt)
#pragma unroll
      for (int r = 0; r < 4; ++r)
        lds16[(16384u + SWZ(mt * 16 + g * 4 + r, (wv * 16 + l15) * 2)) >> 1] = f2bf(qacc[mt][r]);
  }

  // ---- phase KV: K -> buf3, V stays in regs (repacked to PV A-frags) ----
  unsigned vw[4][2];   // [mt][h] = pk2(V[tok2=mt*16+g*4+2h(+1)][ch=wv*16+l15])
  {
    const float bkK = bws[64 + wv * 16 + l15];
    const float bkV = bws[128 + wv * 16 + l15];
    f32x4 kacc[4], vacc[4];
#pragma unroll
    for (int mt = 0; mt < 4; ++mt) {
      kacc[mt] = (f32x4){bkK, bkK, bkK, bkK};
      vacc[mt] = (f32x4){bkV, bkV, bkV, bkV};
    }
#pragma unroll
    for (int kt = 0; kt < 2; ++kt) {
      const bf16x8 wkB = wsf[512 + (wv * 2 + kt) * 64 + lane];
      const bf16x8 wvB = wsf[512 + ((4 + wv) * 2 + kt) * 64 + lane];
#pragma unroll
      for (int mt = 0; mt < 4; ++mt) {
        const bf16x8 kvA = *(const bf16x8*)(lds + 8192 + SWZ(mt * 16 + l15, (kt * 32 + g * 8) * 2));
        kacc[mt] = __builtin_amdgcn_mfma_f32_16x16x32_bf16(kvA, wkB, kacc[mt], 0, 0, 0);
        vacc[mt] = __builtin_amdgcn_mfma_f32_16x16x32_bf16(kvA, wvB, vacc[mt], 0, 0, 0);
      }
    }
#pragma unroll
    for (int mt = 0; mt < 4; ++mt) {
#pragma unroll
      for (int r = 0; r < 4; ++r)
        lds16[(24576u + SWZ(mt * 16 + g * 4 + r, (wv * 16 + l15) * 2)) >> 1] = f2bf(kacc[mt][r]);
#pragma unroll
      for (int h = 0; h < 2; ++h)
        vw[mt][h] = pk2(vacc[mt][2 * h], vacc[mt][2 * h + 1]);
    }
  }

  // ---- QK^T: x32 MFMA, zero-padded K (16 real ch + 16 zeros); wave-local LDS ----
  f32x4 sc[4][4];   // scores^T: col = tok1 = l&15, row = tok2 = (l>>4)*4 + r
  {
    const unsigned padmask = (g < 2) ? 0xFFFFFFFFu : 0u;
    bf16x8 kA32[4], qB32[4];
#pragma unroll
    for (int mt = 0; mt < 4; ++mt) {
      const unsigned byo = SWZ(mt * 16 + l15, (wv * 16 + (g & 1) * 8) * 2);
      u32x4v ka = *(const u32x4v*)(lds + 24576 + byo);
      u32x4v qa = *(const u32x4v*)(lds + 16384 + byo);
      ka &= padmask; qa &= padmask;
      kA32[mt] = u2bf(ka);
      qB32[mt] = u2bf(qa);
    }
#pragma unroll
    for (int mt = 0; mt < 4; ++mt)
#pragma unroll
      for (int nt = 0; nt < 4; ++nt)
        sc[mt][nt] = __builtin_amdgcn_mfma_f32_16x16x32_bf16(kA32[mt], qB32[nt], zero4, 0, 0, 0);
  }

  // ---- softmax over tok2 per column tok1 (exp2 domain; scale folded in wq) ----
  // P left unnormalized; 1/sum folded into PV output (per-lane: tok1 = l15).
  float sinv[4];
#pragma unroll
  for (int nt = 0; nt < 4; ++nt) {
    float m = sc[0][nt][0];
#pragma unroll
    for (int mt = 0; mt < 4; ++mt)
#pragma unroll
      for (int r = 0; r < 4; ++r) m = fmaxf(m, sc[mt][nt][r]);
    m = fmaxf(m, __shfl_xor(m, 16));
    m = fmaxf(m, __shfl_xor(m, 32));
    float sum = 0.f;
#pragma unroll
    for (int mt = 0; mt < 4; ++mt)
#pragma unroll
      for (int r = 0; r < 4; ++r) {
        const float e = exp2f(sc[mt][nt][r] - m);
        sc[mt][nt][r] = e;
        sum += e;
      }
    sum += __shfl_xor(sum, 16);
    sum += __shfl_xor(sum, 32);
    sinv[nt] = 1.0f / sum;
  }
  __syncthreads();  // barrier 2: all buf0/buf1 reads done; buf0 may be overwritten

  // ---- PV: out^T[ch_loc][tok1] = V^T · P~^T over tok2 (2 x32 steps).
  // Consistent bijection slot(kt,g,e=2j+eb) -> tok2 = (2kt+(j>>1))*16 + g*4 + 2(j&1) + eb;
  // P/V C-frags repack in-lane (pk2) as B/A-frags: no LDS, no shuffles.
  f32x4 oacc[4];
#pragma unroll
  for (int nt = 0; nt < 4; ++nt) oacc[nt] = zero4;
#pragma unroll
  for (int kt = 0; kt < 2; ++kt) {
    const bf16x8 vA = u2bf((u32x4v){vw[2 * kt][0], vw[2 * kt][1],
                                    vw[2 * kt + 1][0], vw[2 * kt + 1][1]});
#pragma unroll
    for (int nt = 0; nt < 4; ++nt) {
      const bf16x8 pB = u2bf((u32x4v){pk2(sc[2 * kt][nt][0], sc[2 * kt][nt][1]),
                                      pk2(sc[2 * kt][nt][2], sc[2 * kt][nt][3]),
                                      pk2(sc[2 * kt + 1][nt][0], sc[2 * kt + 1][nt][1]),
                                      pk2(sc[2 * kt + 1][nt][2], sc[2 * kt + 1][nt][3])});
      oacc[nt] = __builtin_amdgcn_mfma_f32_16x16x32_bf16(vA, pB, oacc[nt], 0, 0, 0);
    }
  }
  // attn_out[tok][wv*16 + g*4 + r] -> buf0 own cols (D: col=tok1=l&15, row=ch_loc=g*4+r)
#pragma unroll
  for (int nt = 0; nt < 4; ++nt)
#pragma unroll
    for (int r = 0; r < 4; ++r)
      lds16[SWZ(nt * 16 + l15, (wv * 16 + g * 4 + r) * 2) >> 1] = f2bf(oacc[nt][r] * sinv[nt]);
  __syncthreads();  // barrier 3: attn_out exchange

  // ---- output projection: final^T[c_out][tok], wave owns c_out tile wv ----
  float bo[4];
#pragma unroll
  for (int r = 0; r < 4; ++r) bo[r] = bws[192 + wv * 16 + g * 4 + r];
  f32x4 facc[4];
#pragma unroll
  for (int nt = 0; nt < 4; ++nt) facc[nt] = (f32x4){bo[0], bo[1], bo[2], bo[3]};
#pragma unroll
  for (int kt = 0; kt < 2; ++kt) {
    const bf16x8 woA = wsf[1536 + (wv * 2 + kt) * 64 + lane];
#pragma unroll
    for (int nt = 0; nt < 4; ++nt) {
      const bf16x8 aB = *(const bf16x8*)(lds + SWZ(nt * 16 + l15, (kt * 32 + g * 8) * 2));
      facc[nt] = __builtin_amdgcn_mfma_f32_16x16x32_bf16(woA, aB, facc[nt], 0, 0, 0);
    }
  }
  float* ob = out + (size_t)b * 4194304 + (size_t)(wv * 16) * 65536 + (size_t)y0 * 256 + x0;
#pragma unroll
  for (int nt = 0; nt < 4; ++nt)
#pragma unroll
    for (int r = 0; r < 4; ++r) {
      const unsigned tk = nt * 16 + l15;
      ob[(size_t)(g * 4 + r) * 65536 + (tk >> 3) * 256 + (tk & 7)] = facc[nt][r];
    }
}

extern "C" void kernel_launch(void* const* d_in, const int* in_sizes, int n_in,
                              void* d_out, int out_size, void* d_ws, size_t ws_size,
                              hipStream_t stream) {
  const float* qf   = (const float*)d_in[0];
  const float* kvf  = (const float*)d_in[1];
  const float* wq   = (const float*)d_in[2];
  const float* bq   = (const float*)d_in[3];
  const float* wkv  = (const float*)d_in[4];
  const float* bkv  = (const float*)d_in[5];
  const float* wdw  = (const float*)d_in[6];
  const float* wout = (const float*)d_in[7];
  const float* bout = (const float*)d_in[8];
  (void)in_sizes; (void)n_in; (void)out_size; (void)ws_size;

  prep_weights<<<1, 256, 0, stream>>>(wq, wkv, wout, bq, bkv, bout, (unsigned*)d_ws);
  fused_win_attn<<<8192, 256, 0, stream>>>(qf, kvf, wdw, (const unsigned*)d_ws, (float*)d_out);
}

// Round 6
// 217.349 us; speedup vs baseline: 1.4148x; 1.0076x over previous
//
#include <hip/hip_runtime.h>
#include <hip/hip_bf16.h>

typedef __bf16 bf16x8 __attribute__((ext_vector_type(8)));
typedef float  f32x4  __attribute__((ext_vector_type(4)));
typedef unsigned u32x4v __attribute__((ext_vector_type(4)));

#define QSCALE 0.25f
#define LOG2E  1.4426950408889634f

// f32 -> bf16 via compiler fptrunc (RNE); backend may fuse pairs to v_cvt_pk_bf16_f32
static __device__ __forceinline__ unsigned short f2bf(float x) {
  union { __bf16 h; unsigned short u; } c;
  c.h = (__bf16)x;
  return c.u;
}
static __device__ __forceinline__ unsigned pk2(float a, float b) {
  union { __bf16 h[2]; unsigned u; } c;
  c.h[0] = (__bf16)a; c.h[1] = (__bf16)b;
  return c.u;
}
static __device__ __forceinline__ bf16x8 u2bf(u32x4v x) {
  union { u32x4v u; bf16x8 b; } c; c.u = x; return c.b;
}

// LDS tile rows of 128 B ([tok][ch] bf16); XOR-swizzle byte bits 4-6 by row&7.
#define SWZ(tk, ch2b) ((unsigned)((tk) * 128 + ((ch2b) ^ (((tk) & 7) << 4))))

// ---------------------------------------------------------------------------
// Prologue: weights -> bf16 MFMA fragments in d_ws (proven layout).
// ---------------------------------------------------------------------------
__global__ void prep_weights(const float* __restrict__ wq, const float* __restrict__ wkv,
                             const float* __restrict__ wout, const float* __restrict__ bq,
                             const float* __restrict__ bkv, const float* __restrict__ bout,
                             unsigned* __restrict__ ws32) {
  const unsigned t = threadIdx.x;
  for (unsigned e = t; e < 2048; e += 256) {
    const unsigned fid = e >> 6, lane = e & 63;
    const unsigned l15 = lane & 15, g = lane >> 4;
    float v[8];
    if (fid < 8) {                     // WQ (scale*log2e folded)
      const unsigned nt = fid >> 1, kt = fid & 1, n = nt * 16 + l15;
#pragma unroll
      for (int i = 0; i < 8; ++i) v[i] = wq[(kt * 32 + g * 8 + i) * 64 + n] * (QSCALE * LOG2E);
    } else if (fid < 24) {             // WKV
      const unsigned f = fid - 8, nt = f >> 1, kt = f & 1, n = nt * 16 + l15;
#pragma unroll
      for (int i = 0; i < 8; ++i) v[i] = wkv[(kt * 32 + g * 8 + i) * 128 + n];
    } else {                           // WOUT^T: A[m=c_out][k=c_in] = wout[c_in][c_out]
      const unsigned f = fid - 24, mt = f >> 1, kt = f & 1, m = mt * 16 + l15;
#pragma unroll
      for (int i = 0; i < 8; ++i) v[i] = wout[(kt * 32 + g * 8 + i) * 64 + m];
    }
#pragma unroll
    for (int w = 0; w < 4; ++w) ws32[e * 4 + w] = pk2(v[2 * w], v[2 * w + 1]);
  }
  float* bws = (float*)(ws32 + 8192);
  if (t < 64)       bws[t] = bq[t] * (QSCALE * LOG2E);
  else if (t < 192) bws[t] = bkv[t - 64];
  else if (t < 256) bws[t] = bout[t - 192];
}

// ---------------------------------------------------------------------------
// Main: 1 block (4 waves) per 8x8 window; wave = head. Only 16x16x32 MFMA.
// LDS: buf0 [0,8K) q-window -> (after bar2) attn_out | buf1 [8K,16K) conv kv
//      buf2 [16K,24K) q_proj | buf3 [24K,32K) K
// P and V^T never touch LDS (C-frag -> A/B-frag bijection, in-lane repack).
// ---------------------------------------------------------------------------
__launch_bounds__(256, 5)
__global__ void fused_win_attn(const float* __restrict__ qf, const float* __restrict__ kvf,
                               const float* __restrict__ wdw, const unsigned* __restrict__ ws32,
                               float* __restrict__ out) {
  __shared__ __align__(16) char lds[32768];
  unsigned short* lds16 = (unsigned short*)lds;
  unsigned* lds32p = (unsigned*)lds;

  // XCD-chunked swizzle: consecutive launch-bids on one XCD sweep x-adjacent windows
  const unsigned bid = blockIdx.x;
  const unsigned wid = (bid & 7) * 1024 + (bid >> 3);
  const unsigned b = wid >> 10, rem = wid & 1023;
  const unsigned y0 = (rem >> 5) * 8, x0 = (rem & 31) * 8;

  const unsigned t = threadIdx.x;
  const unsigned lane = t & 63;
  const unsigned wv = t >> 6;           // wave id = head id
  const unsigned l15 = lane & 15, g = lane >> 4;
  const unsigned tok = lane;            // boundary conv: lane <-> token

  // ---- stage q window -> buf0: float4 loads, lane = channel ----
  {
    const float* qbase = qf + ((size_t)b * 64 + lane) * 65536 + (size_t)y0 * 256 + x0;
#pragma unroll
    for (int j = 0; j < 4; ++j) {
      const unsigned hr = (unsigned)j * 4 + wv;
      const unsigned row = hr >> 1, x4 = (hr & 1) * 4;
      const f32x4 v = *(const f32x4*)(qbase + row * 256 + x4);
#pragma unroll
      for (int i = 0; i < 4; ++i)
        lds16[SWZ(row * 8 + x4 + i, lane * 2) >> 1] = f2bf(v[i]);
    }
  }

  // ---- depthwise 3x3 conv (f32) -> buf1 ----
  const bool edge = (y0 == 0) || (y0 == 248) || (x0 == 0) || (x0 == 248);
  if (!edge) {
    // interior: 4 ch x 4 px per thread, float4 tap loads (no clamping needed)
    const unsigned cg = t >> 4, pos = t & 15;
    const unsigned row = pos >> 1, xh = pos & 1;
    const float* kb0 = kvf + ((size_t)b * 64 + cg * 4) * 65536
                     + (size_t)(y0 + row - 1) * 256 + (x0 + xh * 4 - 4);
    float acc[4][4];
#pragma unroll
    for (int c = 0; c < 4; ++c) {
      const float* cp = kb0 + (size_t)c * 65536;
      float L[3][12];
#pragma unroll
      for (int dr = 0; dr < 3; ++dr)
#pragma unroll
        for (int s = 0; s < 3; ++s) {
          const f32x4 v = *(const f32x4*)(cp + dr * 256 + s * 4);
          L[dr][s * 4 + 0] = v[0]; L[dr][s * 4 + 1] = v[1];
          L[dr][s * 4 + 2] = v[2]; L[dr][s * 4 + 3] = v[3];
        }
      const float* wp = wdw + (cg * 4 + (unsigned)c) * 9;
      float w[9];
#pragma unroll
      for (int k = 0; k < 9; ++k) w[k] = wp[k];
#pragma unroll
      for (int i = 0; i < 4; ++i) {
        float a = 0.f;
#pragma unroll
        for (int dr = 0; dr < 3; ++dr)
#pragma unroll
          for (int dx = 0; dx < 3; ++dx)
            a = fmaf(L[dr][i + 3 + dx], w[dr * 3 + dx], a);
        acc[c][i] = a;
      }
    }
#pragma unroll
    for (int i = 0; i < 4; ++i) {
      const unsigned tk = row * 8 + xh * 4 + (unsigned)i;
      lds32p[(8192u + SWZ(tk, cg * 8)) >> 2]      = pk2(acc[0][i], acc[1][i]);
      lds32p[(8192u + SWZ(tk, cg * 8 + 4)) >> 2]  = pk2(acc[2][i], acc[3][i]);
    }
  } else {
    // boundary: scalar clamped path (wave wv does ch [wv*16, wv*16+16))
    const int yy = (int)(y0 + (tok >> 3)), xx = (int)(x0 + (tok & 7));
    int off[9]; float msk[9];
#pragma unroll
    for (int dy = -1; dy <= 1; ++dy)
#pragma unroll
      for (int dx = -1; dx <= 1; ++dx) {
        const int k = (dy + 1) * 3 + (dx + 1);
        int yq = yy + dy, xq = xx + dx;
        const bool ok = (yq >= 0) && (yq < 256) && (xq >= 0) && (xq < 256);
        yq = yq < 0 ? 0 : (yq > 255 ? 255 : yq);
        xq = xq < 0 ? 0 : (xq > 255 ? 255 : xq);
        off[k] = yq * 256 + xq;
        msk[k] = ok ? 1.f : 0.f;
      }
    const float* kb = kvf + (size_t)b * 4194304 + (size_t)(wv * 16) * 65536;
    const float* wp0 = wdw + wv * 16 * 9;
#pragma unroll
    for (int c2 = 0; c2 < 8; ++c2) {
      float acc[2];
#pragma unroll
      for (int hh = 0; hh < 2; ++hh) {
        const float* cb = kb + (size_t)(c2 * 2 + hh) * 65536;
        const float* wp = wp0 + (c2 * 2 + hh) * 9;
        float a = 0.f;
#pragma unroll
        for (int k = 0; k < 9; ++k) a = fmaf(cb[off[k]], wp[k] * msk[k], a);
        acc[hh] = a;
      }
      lds32p[(8192u + SWZ(tok, (wv * 16 + c2 * 2) * 2)) >> 2] = pk2(acc[0], acc[1]);
    }
  }
  __syncthreads();  // barrier 1: staged q + conv visible

  const bf16x8* wsf = (const bf16x8*)ws32;
  const float* bws = (const float*)(ws32 + 8192);
  const f32x4 zero4 = (f32x4){0.f, 0.f, 0.f, 0.f};

  // ---- phase Q: q_proj for this head's 16 cols -> buf2 ----
  {
    const float bqv = bws[wv * 16 + l15];
    f32x4 qacc[4];
#pragma unroll
    for (int mt = 0; mt < 4; ++mt) qacc[mt] = (f32x4){bqv, bqv, bqv, bqv};
#pragma unroll
    for (int kt = 0; kt < 2; ++kt) {
      const bf16x8 wqB = wsf[(wv * 2 + kt) * 64 + lane];
#pragma unroll
      for (int mt = 0; mt < 4; ++mt) {
        const bf16x8 qA = *(const bf16x8*)(lds + SWZ(mt * 16 + l15, (kt * 32 + g * 8) * 2));
        qacc[mt] = __builtin_amdgcn_mfma_f32_16x16x32_bf16(qA, wqB, qacc[mt], 0, 0, 0);
      }
    }
    // C-map (verified): col = l&15, row = (l>>4)*4 + r
#pragma unroll
    for (int mt = 0; mt < 4; ++mt)
#pragma unroll
      for (int r = 0; r < 4; ++r)
        lds16[(16384u + SWZ(mt * 16 + g * 4 + r, (wv * 16 + l15) * 2)) >> 1] = f2bf(qacc[mt][r]);
  }

  // ---- phase KV: K -> buf3, V stays in regs (repacked to PV A-frags) ----
  unsigned vw[4][2];   // [mt][h] = pk2(V[tok2=mt*16+g*4+2h(+1)][ch=wv*16+l15])
  {
    const float bkK = bws[64 + wv * 16 + l15];
    const float bkV = bws[128 + wv * 16 + l15];
    f32x4 kacc[4], vacc[4];
#pragma unroll
    for (int mt = 0; mt < 4; ++mt) {
      kacc[mt] = (f32x4){bkK, bkK, bkK, bkK};
      vacc[mt] = (f32x4){bkV, bkV, bkV, bkV};
    }
#pragma unroll
    for (int kt = 0; kt < 2; ++kt) {
      const bf16x8 wkB = wsf[512 + (wv * 2 + kt) * 64 + lane];
      const bf16x8 wvB = wsf[512 + ((4 + wv) * 2 + kt) * 64 + lane];
#pragma unroll
      for (int mt = 0; mt < 4; ++mt) {
        const bf16x8 kvA = *(const bf16x8*)(lds + 8192 + SWZ(mt * 16 + l15, (kt * 32 + g * 8) * 2));
        kacc[mt] = __builtin_amdgcn_mfma_f32_16x16x32_bf16(kvA, wkB, kacc[mt], 0, 0, 0);
        vacc[mt] = __builtin_amdgcn_mfma_f32_16x16x32_bf16(kvA, wvB, vacc[mt], 0, 0, 0);
      }
    }
#pragma unroll
    for (int mt = 0; mt < 4; ++mt) {
#pragma unroll
      for (int r = 0; r < 4; ++r)
        lds16[(24576u + SWZ(mt * 16 + g * 4 + r, (wv * 16 + l15) * 2)) >> 1] = f2bf(kacc[mt][r]);
#pragma unroll
      for (int h = 0; h < 2; ++h)
        vw[mt][h] = pk2(vacc[mt][2 * h], vacc[mt][2 * h + 1]);
    }
  }

  // ---- QK^T: x32 MFMA, zero-padded K (16 real ch + 16 zeros); wave-local LDS ----
  f32x4 sc[4][4];   // scores^T: col = tok1 = l&15, row = tok2 = (l>>4)*4 + r
  {
    const unsigned padmask = (g < 2) ? 0xFFFFFFFFu : 0u;
    bf16x8 kA32[4], qB32[4];
#pragma unroll
    for (int mt = 0; mt < 4; ++mt) {
      const unsigned byo = SWZ(mt * 16 + l15, (wv * 16 + (g & 1) * 8) * 2);
      u32x4v ka = *(const u32x4v*)(lds + 24576 + byo);
      u32x4v qa = *(const u32x4v*)(lds + 16384 + byo);
      ka &= padmask; qa &= padmask;
      kA32[mt] = u2bf(ka);
      qB32[mt] = u2bf(qa);
    }
#pragma unroll
    for (int mt = 0; mt < 4; ++mt)
#pragma unroll
      for (int nt = 0; nt < 4; ++nt)
        sc[mt][nt] = __builtin_amdgcn_mfma_f32_16x16x32_bf16(kA32[mt], qB32[nt], zero4, 0, 0, 0);
  }

  // ---- softmax over tok2 per column tok1 (exp2 domain; scale folded in wq) ----
  float sinv[4];
#pragma unroll
  for (int nt = 0; nt < 4; ++nt) {
    float m = sc[0][nt][0];
#pragma unroll
    for (int mt = 0; mt < 4; ++mt)
#pragma unroll
      for (int r = 0; r < 4; ++r) m = fmaxf(m, sc[mt][nt][r]);
    m = fmaxf(m, __shfl_xor(m, 16));
    m = fmaxf(m, __shfl_xor(m, 32));
    float sum = 0.f;
#pragma unroll
    for (int mt = 0; mt < 4; ++mt)
#pragma unroll
      for (int r = 0; r < 4; ++r) {
        const float e = exp2f(sc[mt][nt][r] - m);
        sc[mt][nt][r] = e;
        sum += e;
      }
    sum += __shfl_xor(sum, 16);
    sum += __shfl_xor(sum, 32);
    sinv[nt] = 1.0f / sum;
  }
  __syncthreads();  // barrier 2: all buf0/buf1 reads done; buf0 may be overwritten

  // ---- PV: out^T[ch_loc][tok1] = V^T · P~^T over tok2 (2 x32 steps).
  // Consistent bijection slot(kt,g,e=2j+eb) -> tok2 = (2kt+(j>>1))*16 + g*4 + 2(j&1) + eb
  f32x4 oacc[4];
#pragma unroll
  for (int nt = 0; nt < 4; ++nt) oacc[nt] = zero4;
#pragma unroll
  for (int kt = 0; kt < 2; ++kt) {
    const bf16x8 vA = u2bf((u32x4v){vw[2 * kt][0], vw[2 * kt][1],
                                    vw[2 * kt + 1][0], vw[2 * kt + 1][1]});
#pragma unroll
    for (int nt = 0; nt < 4; ++nt) {
      const bf16x8 pB = u2bf((u32x4v){pk2(sc[2 * kt][nt][0], sc[2 * kt][nt][1]),
                                      pk2(sc[2 * kt][nt][2], sc[2 * kt][nt][3]),
                                      pk2(sc[2 * kt + 1][nt][0], sc[2 * kt + 1][nt][1]),
                                      pk2(sc[2 * kt + 1][nt][2], sc[2 * kt + 1][nt][3])});
      oacc[nt] = __builtin_amdgcn_mfma_f32_16x16x32_bf16(vA, pB, oacc[nt], 0, 0, 0);
    }
  }
  // attn_out[tok][wv*16 + g*4 + r] -> buf0 own cols
#pragma unroll
  for (int nt = 0; nt < 4; ++nt)
#pragma unroll
    for (int r = 0; r < 4; ++r)
      lds16[SWZ(nt * 16 + l15, (wv * 16 + g * 4 + r) * 2) >> 1] = f2bf(oacc[nt][r] * sinv[nt]);
  __syncthreads();  // barrier 3: attn_out exchange

  // ---- output projection: final^T[c_out][tok], wave owns c_out tile wv ----
  float bo[4];
#pragma unroll
  for (int r = 0; r < 4; ++r) bo[r] = bws[192 + wv * 16 + g * 4 + r];
  f32x4 facc[4];
#pragma unroll
  for (int nt = 0; nt < 4; ++nt) facc[nt] = (f32x4){bo[0], bo[1], bo[2], bo[3]};
#pragma unroll
  for (int kt = 0; kt < 2; ++kt) {
    const bf16x8 woA = wsf[1536 + (wv * 2 + kt) * 64 + lane];
#pragma unroll
    for (int nt = 0; nt < 4; ++nt) {
      const bf16x8 aB = *(const bf16x8*)(lds + SWZ(nt * 16 + l15, (kt * 32 + g * 8) * 2));
      facc[nt] = __builtin_amdgcn_mfma_f32_16x16x32_bf16(woA, aB, facc[nt], 0, 0, 0);
    }
  }
  float* ob = out + (size_t)b * 4194304 + (size_t)(wv * 16) * 65536 + (size_t)y0 * 256 + x0;
#pragma unroll
  for (int nt = 0; nt < 4; ++nt)
#pragma unroll
    for (int r = 0; r < 4; ++r) {
      const unsigned tk = nt * 16 + l15;
      ob[(size_t)(g * 4 + r) * 65536 + (tk >> 3) * 256 + (tk & 7)] = facc[nt][r];
    }
}

extern "C" void kernel_launch(void* const* d_in, const int* in_sizes, int n_in,
                              void* d_out, int out_size, void* d_ws, size_t ws_size,
                              hipStream_t stream) {
  const float* qf   = (const float*)d_in[0];
  const float* kvf  = (const float*)d_in[1];
  const float* wq   = (const float*)d_in[2];
  const float* bq   = (const float*)d_in[3];
  const float* wkv  = (const float*)d_in[4];
  const float* bkv  = (const float*)d_in[5];
  const float* wdw  = (const float*)d_in[6];
  const float* wout = (const float*)d_in[7];
  const float* bout = (const float*)d_in[8];
  (void)in_sizes; (void)n_in; (void)out_size; (void)ws_size;

  prep_weights<<<1, 256, 0, stream>>>(wq, wkv, wout, bq, bkv, bout, (unsigned*)d_ws);
  fused_win_attn<<<8192, 256, 0, stream>>>(qf, kvf, wdw, (const unsigned*)d_ws, (float*)d_out);
}